// Round 1
// baseline (360.886 us; speedup 1.0000x reference)
//
#include <hip/hip_runtime.h>
#include <hip/hip_bf16.h>

#define BF16 __hip_bfloat16

typedef __bf16 bf16x8 __attribute__((ext_vector_type(8)));
typedef float floatx4 __attribute__((ext_vector_type(4)));

__device__ __forceinline__ void glds16(const void* g, void* l) {
    __builtin_amdgcn_global_load_lds(
        (const __attribute__((address_space(1))) void*)g,
        (__attribute__((address_space(3))) void*)l, 16, 0, 0);
}

// ---------------- transpose + fp32->bf16 convert ----------------
// in: fp32 [z][R][C], out: bf16 [z][C][R].  R,C multiples of 32.
__global__ __launch_bounds__(256) void transpose_cvt(const float* __restrict__ in,
                                                     BF16* __restrict__ out,
                                                     int R, int C) {
    __shared__ float tile[32][33];
    size_t boff = (size_t)blockIdx.z * R * C;
    const float* ip = in + boff;
    BF16* op = out + boff;
    int tx = threadIdx.x & 31, ty = threadIdx.x >> 5;
    int r0 = blockIdx.y << 5, c0 = blockIdx.x << 5;
#pragma unroll
    for (int i = 0; i < 4; ++i)
        tile[ty + i * 8][tx] = ip[(size_t)(r0 + ty + i * 8) * C + c0 + tx];
    __syncthreads();
#pragma unroll
    for (int i = 0; i < 4; ++i)
        op[(size_t)(c0 + ty + i * 8) * R + r0 + tx] = __float2bfloat16(tile[tx][ty + i * 8]);
}

// ---------------- ROI align ----------------
// featT bf16 [B][100][136][256]; feats bf16 [1024][12544] (rows >=1000 zeroed)
__global__ __launch_bounds__(256) void roi_align_k(const BF16* __restrict__ featT,
                                                   const float* __restrict__ boxes,
                                                   const int* __restrict__ roi_batch,
                                                   BF16* __restrict__ feats) {
    __shared__ float lbuf[12544];
    int roi = blockIdx.x;
    int t = threadIdx.x;  // channel
    BF16* orow = feats + (size_t)roi * 12544;
    if (roi >= 1000) {
        for (int i = t; i < 12544; i += 256) orow[i] = __float2bfloat16(0.0f);
        return;
    }
    int b = roi_batch[roi];
    float x1 = boxes[roi * 4 + 0] * 0.125f;
    float y1 = boxes[roi * 4 + 1] * 0.125f;
    float x2 = boxes[roi * 4 + 2] * 0.125f;
    float y2 = boxes[roi * 4 + 3] * 0.125f;
    float bw = fmaxf(x2 - x1, 1.0f) * (1.0f / 7.0f);
    float bh = fmaxf(y2 - y1, 1.0f) * (1.0f / 7.0f);
    const BF16* fb = featT + (size_t)b * (100 * 136 * 256);

    for (int cell = 0; cell < 49; ++cell) {
        int oy = cell / 7, ox = cell - oy * 7;
        float a = 0.0f;
#pragma unroll
        for (int s = 0; s < 4; ++s) {
            int sy = s >> 1, sx = s & 1;
            float yc = y1 + ((float)oy + ((float)sy + 0.5f) * 0.5f) * bh;
            float xc = x1 + ((float)ox + ((float)sx + 0.5f) * 0.5f) * bw;
            yc = fminf(fmaxf(yc, 0.0f), 99.0f);
            xc = fminf(fmaxf(xc, 0.0f), 135.0f);
            float y0f = floorf(yc), x0f = floorf(xc);
            int y0 = (int)y0f, x0 = (int)x0f;
            int y1i = min(y0 + 1, 99), x1i = min(x0 + 1, 135);
            float ly = yc - y0f, lx = xc - x0f;
            float w00 = (1.0f - ly) * (1.0f - lx);
            float w01 = (1.0f - ly) * lx;
            float w10 = ly * (1.0f - lx);
            float w11 = ly * lx;
            int i00 = (y0 * 136 + x0) * 256 + t;
            int i01 = (y0 * 136 + x1i) * 256 + t;
            int i10 = (y1i * 136 + x0) * 256 + t;
            int i11 = (y1i * 136 + x1i) * 256 + t;
            a += w00 * __bfloat162float(fb[i00]) + w01 * __bfloat162float(fb[i01]) +
                 w10 * __bfloat162float(fb[i10]) + w11 * __bfloat162float(fb[i11]);
        }
        lbuf[t * 49 + cell] = a * 0.25f;  // stride 49 (odd) -> conflict-free
    }
    __syncthreads();
    for (int i = t; i < 12544; i += 256) orow[i] = __float2bfloat16(lbuf[i]);
}

// ---------------- bf16 MFMA GEMM, B^T input, fused bias+ReLU ----------------
// A bf16 [1024][K], Bt bf16 [N][K], out bf16 [1024][N]; 64x64 tile, BK=32
__global__ __launch_bounds__(256) void gemm_bt(const BF16* __restrict__ A,
                                               const BF16* __restrict__ Bt,
                                               const float* __restrict__ bias,
                                               BF16* __restrict__ out,
                                               int N, int K, int relu) {
    __shared__ short ldsA[64 * 32];
    __shared__ short ldsB[64 * 32];
    int w = threadIdx.x >> 6, l = threadIdx.x & 63;
    int wm = w & 1, wn = w >> 1;
    int tm = blockIdx.y, tn = blockIdx.x;
    floatx4 acc00 = {0.f, 0.f, 0.f, 0.f};
    floatx4 acc01 = {0.f, 0.f, 0.f, 0.f};
    floatx4 acc10 = {0.f, 0.f, 0.f, 0.f};
    floatx4 acc11 = {0.f, 0.f, 0.f, 0.f};

    // staging: wave w loads rows [w*16, w*16+16); lane l -> row w*16+l/4, 16B chunk l%4
    const char* gA = (const char*)(A + (size_t)(tm * 64 + w * 16 + (l >> 2)) * K + (l & 3) * 8);
    const char* gB = (const char*)(Bt + (size_t)(tn * 64 + w * 16 + (l >> 2)) * K + (l & 3) * 8);
    void* lA = (void*)&ldsA[w * 512];
    void* lB = (void*)&ldsB[w * 512];

    int c = l & 15, q = l >> 4;
    int raoff = (wm * 32 + c) * 32 + q * 8;
    int rboff = (wn * 32 + c) * 32 + q * 8;
    int K32 = K >> 5;
    for (int kb = 0; kb < K32; ++kb) {
        glds16(gA, lA);
        glds16(gB, lB);
        gA += 64;  // 32 bf16 = 64 bytes per K-step
        gB += 64;
        __syncthreads();
        bf16x8 a0 = *(const bf16x8*)&ldsA[raoff];
        bf16x8 a1 = *(const bf16x8*)&ldsA[raoff + 16 * 32];
        bf16x8 b0 = *(const bf16x8*)&ldsB[rboff];
        bf16x8 b1 = *(const bf16x8*)&ldsB[rboff + 16 * 32];
        acc00 = __builtin_amdgcn_mfma_f32_16x16x32_bf16(a0, b0, acc00, 0, 0, 0);
        acc01 = __builtin_amdgcn_mfma_f32_16x16x32_bf16(a0, b1, acc01, 0, 0, 0);
        acc10 = __builtin_amdgcn_mfma_f32_16x16x32_bf16(a1, b0, acc10, 0, 0, 0);
        acc11 = __builtin_amdgcn_mfma_f32_16x16x32_bf16(a1, b1, acc11, 0, 0, 0);
        __syncthreads();
    }
    // D layout: col = lane&15, row = (lane>>4)*4 + reg
    int colBase = tn * 64 + wn * 32 + c;
    int rowBase = tm * 64 + wm * 32 + q * 4;
    float bias0 = bias[colBase];
    float bias1 = bias[colBase + 16];
#pragma unroll
    for (int r = 0; r < 4; ++r) {
        float v;
        v = acc00[r] + bias0; if (relu) v = fmaxf(v, 0.0f);
        out[(size_t)(rowBase + r) * N + colBase] = __float2bfloat16(v);
        v = acc01[r] + bias1; if (relu) v = fmaxf(v, 0.0f);
        out[(size_t)(rowBase + r) * N + colBase + 16] = __float2bfloat16(v);
        v = acc10[r] + bias0; if (relu) v = fmaxf(v, 0.0f);
        out[(size_t)(rowBase + 16 + r) * N + colBase] = __float2bfloat16(v);
        v = acc11[r] + bias1; if (relu) v = fmaxf(v, 0.0f);
        out[(size_t)(rowBase + 16 + r) * N + colBase + 16] = __float2bfloat16(v);
    }
}

// ---------------- cls/bbox heads + softmax + decode ----------------
__global__ __launch_bounds__(256) void head_k(const BF16* __restrict__ h2,
                                              const float* __restrict__ cls_w,
                                              const float* __restrict__ cls_b,
                                              const float* __restrict__ bbox_w,
                                              const float* __restrict__ bbox_b,
                                              const float* __restrict__ boxes,
                                              float* __restrict__ out) {
    int w = threadIdx.x >> 6, l = threadIdx.x & 63;
    int roi = blockIdx.x * 4 + w;
    if (roi >= 1000) return;
    float acc[10];
#pragma unroll
    for (int j = 0; j < 10; ++j) acc[j] = 0.0f;
    const BF16* hr = h2 + (size_t)roi * 1024;
    for (int k = l; k < 1024; k += 64) {
        float h = __bfloat162float(hr[k]);
        acc[0] += h * cls_w[k * 2 + 0];
        acc[1] += h * cls_w[k * 2 + 1];
#pragma unroll
        for (int j = 0; j < 8; ++j) acc[2 + j] += h * bbox_w[k * 8 + j];
    }
#pragma unroll
    for (int j = 0; j < 10; ++j) {
#pragma unroll
        for (int off = 32; off > 0; off >>= 1) acc[j] += __shfl_down(acc[j], off);
    }
    if (l == 0) {
        float s0 = acc[0] + cls_b[0], s1 = acc[1] + cls_b[1];
        float m = fmaxf(s0, s1);
        float e0 = expf(s0 - m), e1 = expf(s1 - m);
        float inv = 1.0f / (e0 + e1);

        float bx1 = boxes[roi * 4 + 0], by1 = boxes[roi * 4 + 1];
        float bx2 = boxes[roi * 4 + 2], by2 = boxes[roi * 4 + 3];
        float pw = bx2 - bx1, ph = by2 - by1;
        float cx = bx1 + 0.5f * pw, cy = by1 + 0.5f * ph;
        const float CLAMPV = 4.135166556742356f;  // log(1000/16)
        float* orow = out + roi * 10;
#pragma unroll
        for (int cl = 0; cl < 2; ++cl) {
            float dx = (acc[2 + cl * 4 + 0] + bbox_b[cl * 4 + 0]) * 0.1f;
            float dy = (acc[2 + cl * 4 + 1] + bbox_b[cl * 4 + 1]) * 0.1f;
            float dw = fminf((acc[2 + cl * 4 + 2] + bbox_b[cl * 4 + 2]) * 0.2f, CLAMPV);
            float dh = fminf((acc[2 + cl * 4 + 3] + bbox_b[cl * 4 + 3]) * 0.2f, CLAMPV);
            float pcx = dx * pw + cx, pcy = dy * ph + cy;
            float pww = expf(dw) * pw, phh = expf(dh) * ph;
            orow[cl * 4 + 0] = fminf(fmaxf(pcx - 0.5f * pww, 0.0f), 1088.0f);
            orow[cl * 4 + 1] = fminf(fmaxf(pcy - 0.5f * phh, 0.0f), 800.0f);
            orow[cl * 4 + 2] = fminf(fmaxf(pcx + 0.5f * pww, 0.0f), 1088.0f);
            orow[cl * 4 + 3] = fminf(fmaxf(pcy + 0.5f * phh, 0.0f), 800.0f);
        }
        orow[8] = e0 * inv;
        orow[9] = e1 * inv;
    }
}

extern "C" void kernel_launch(void* const* d_in, const int* in_sizes, int n_in,
                              void* d_out, int out_size, void* d_ws, size_t ws_size,
                              hipStream_t stream) {
    const float* features = (const float*)d_in[0];
    const float* boxes    = (const float*)d_in[1];
    const int*   roi_b    = (const int*)d_in[2];
    const float* fc1_w    = (const float*)d_in[3];
    const float* fc1_b    = (const float*)d_in[4];
    const float* fc2_w    = (const float*)d_in[5];
    const float* fc2_b    = (const float*)d_in[6];
    const float* cls_w    = (const float*)d_in[7];
    const float* cls_b    = (const float*)d_in[8];
    const float* bbox_w   = (const float*)d_in[9];
    const float* bbox_b   = (const float*)d_in[10];
    float* out = (float*)d_out;

    char* ws = (char*)d_ws;
    BF16* featT = (BF16*)(ws + 0);           // 2*100*136*256*2  = 13,926,400 B
    BF16* w1t   = (BF16*)(ws + 13926400);    // 1024*12544*2     = 25,690,112 B
    BF16* w2t   = (BF16*)(ws + 39616512);    // 1024*1024*2      =  2,097,152 B
    BF16* feats = (BF16*)(ws + 41713664);    // 1024*12544*2     = 25,690,112 B
    BF16* h1    = (BF16*)(ws + 67403776);    // 1024*1024*2      =  2,097,152 B
    BF16* h2    = (BF16*)(ws + 69500928);    // 1024*1024*2      =  2,097,152 B

    // features [2,256,13600] -> featT [2,13600,256] bf16
    transpose_cvt<<<dim3(425, 8, 2), 256, 0, stream>>>(features, featT, 256, 13600);
    // fc1_w [12544,1024] -> w1t [1024,12544] bf16
    transpose_cvt<<<dim3(32, 392, 1), 256, 0, stream>>>(fc1_w, w1t, 12544, 1024);
    // fc2_w [1024,1024] -> w2t [1024,1024] bf16
    transpose_cvt<<<dim3(32, 32, 1), 256, 0, stream>>>(fc2_w, w2t, 1024, 1024);

    roi_align_k<<<1024, 256, 0, stream>>>(featT, boxes, roi_b, feats);

    gemm_bt<<<dim3(16, 16), 256, 0, stream>>>(feats, w1t, fc1_b, h1, 1024, 12544, 1);
    gemm_bt<<<dim3(16, 16), 256, 0, stream>>>(h1, w2t, fc2_b, h2, 1024, 1024, 1);

    head_k<<<250, 256, 0, stream>>>(h2, cls_w, cls_b, bbox_w, bbox_b, boxes, out);
}

// Round 2
// 269.159 us; speedup vs baseline: 1.3408x; 1.3408x over previous
//
#include <hip/hip_runtime.h>
#include <hip/hip_bf16.h>

#define BF16 __hip_bfloat16

typedef __bf16 bf16x8 __attribute__((ext_vector_type(8)));
typedef float floatx4 __attribute__((ext_vector_type(4)));

__device__ __forceinline__ void glds16(const void* g, void* l) {
    __builtin_amdgcn_global_load_lds(
        (const __attribute__((address_space(1))) void*)g,
        (__attribute__((address_space(3))) void*)l, 16, 0, 0);
}

// ---------------- transpose + fp32->bf16 convert ----------------
// in: fp32 [z][R][C], out: bf16 [z][C][R].  R,C multiples of 32.
__global__ __launch_bounds__(256) void transpose_cvt(const float* __restrict__ in,
                                                     BF16* __restrict__ out,
                                                     int R, int C) {
    __shared__ float tile[32][33];
    size_t boff = (size_t)blockIdx.z * R * C;
    const float* ip = in + boff;
    BF16* op = out + boff;
    int tx = threadIdx.x & 31, ty = threadIdx.x >> 5;
    int r0 = blockIdx.y << 5, c0 = blockIdx.x << 5;
#pragma unroll
    for (int i = 0; i < 4; ++i)
        tile[ty + i * 8][tx] = ip[(size_t)(r0 + ty + i * 8) * C + c0 + tx];
    __syncthreads();
#pragma unroll
    for (int i = 0; i < 4; ++i)
        op[(size_t)(c0 + ty + i * 8) * R + r0 + tx] = __float2bfloat16(tile[tx][ty + i * 8]);
}

// ---------------- ROI align ----------------
// featT bf16 [B][100][136][256]; feats bf16 [1024][12544] (rows >=1000 zeroed)
__global__ __launch_bounds__(256) void roi_align_k(const BF16* __restrict__ featT,
                                                   const float* __restrict__ boxes,
                                                   const int* __restrict__ roi_batch,
                                                   BF16* __restrict__ feats) {
    __shared__ float lbuf[12544];
    int roi = blockIdx.x;
    int t = threadIdx.x;  // channel
    BF16* orow = feats + (size_t)roi * 12544;
    if (roi >= 1000) {
        for (int i = t; i < 12544; i += 256) orow[i] = __float2bfloat16(0.0f);
        return;
    }
    int b = roi_batch[roi];
    float x1 = boxes[roi * 4 + 0] * 0.125f;
    float y1 = boxes[roi * 4 + 1] * 0.125f;
    float x2 = boxes[roi * 4 + 2] * 0.125f;
    float y2 = boxes[roi * 4 + 3] * 0.125f;
    float bw = fmaxf(x2 - x1, 1.0f) * (1.0f / 7.0f);
    float bh = fmaxf(y2 - y1, 1.0f) * (1.0f / 7.0f);
    const BF16* fb = featT + (size_t)b * (100 * 136 * 256);

    for (int cell = 0; cell < 49; ++cell) {
        int oy = cell / 7, ox = cell - oy * 7;
        float a = 0.0f;
#pragma unroll
        for (int s = 0; s < 4; ++s) {
            int sy = s >> 1, sx = s & 1;
            float yc = y1 + ((float)oy + ((float)sy + 0.5f) * 0.5f) * bh;
            float xc = x1 + ((float)ox + ((float)sx + 0.5f) * 0.5f) * bw;
            yc = fminf(fmaxf(yc, 0.0f), 99.0f);
            xc = fminf(fmaxf(xc, 0.0f), 135.0f);
            float y0f = floorf(yc), x0f = floorf(xc);
            int y0 = (int)y0f, x0 = (int)x0f;
            int y1i = min(y0 + 1, 99), x1i = min(x0 + 1, 135);
            float ly = yc - y0f, lx = xc - x0f;
            float w00 = (1.0f - ly) * (1.0f - lx);
            float w01 = (1.0f - ly) * lx;
            float w10 = ly * (1.0f - lx);
            float w11 = ly * lx;
            int i00 = (y0 * 136 + x0) * 256 + t;
            int i01 = (y0 * 136 + x1i) * 256 + t;
            int i10 = (y1i * 136 + x0) * 256 + t;
            int i11 = (y1i * 136 + x1i) * 256 + t;
            a += w00 * __bfloat162float(fb[i00]) + w01 * __bfloat162float(fb[i01]) +
                 w10 * __bfloat162float(fb[i10]) + w11 * __bfloat162float(fb[i11]);
        }
        lbuf[t * 49 + cell] = a * 0.25f;  // stride 49 (odd) -> conflict-free
    }
    __syncthreads();
    for (int i = t; i < 12544; i += 256) orow[i] = __float2bfloat16(lbuf[i]);
}

// ---------------- split-K bf16 MFMA GEMM, 128x128 tile, double-buffered ----------------
// A bf16 [1024][K], Bt bf16 [1024][K] (N=1024), P fp32 [S][1024][1024] partials.
// grid (8, 8, S); chunk = K/S, chunk % 32 == 0. 256 threads = 4 waves in 2x2.
__global__ __launch_bounds__(256) void gemm_splitk(const BF16* __restrict__ A,
                                                   const BF16* __restrict__ Bt,
                                                   float* __restrict__ P,
                                                   int K, int chunk) {
    __shared__ char lds[2][2][8192];  // [buf][A=0/B=1][128 rows x 64 B]
    int w = threadIdx.x >> 6, l = threadIdx.x & 63;
    int wm = w & 1, wn = w >> 1;
    int tm = blockIdx.y, tn = blockIdx.x, s = blockIdx.z;
    int k0 = s * chunk;

    floatx4 acc[4][4];
#pragma unroll
    for (int i = 0; i < 4; ++i)
#pragma unroll
        for (int j = 0; j < 4; ++j) acc[i][j] = (floatx4){0.f, 0.f, 0.f, 0.f};

    const size_t strideA = (size_t)K * 2;  // bytes per row
    const char* gA = (const char*)A + (size_t)(tm * 128 + w * 16 + (l >> 2)) * strideA
                     + (size_t)k0 * 2 + (size_t)(l & 3) * 16;
    const char* gB = (const char*)Bt + (size_t)(tn * 128 + w * 16 + (l >> 2)) * strideA
                     + (size_t)k0 * 2 + (size_t)(l & 3) * 16;
    size_t rowJump = 64 * strideA;  // +64 rows for second staging issue

    int aoff = (wm * 64 + (l & 15)) * 64 + (l >> 4) * 16;
    int boff = (wn * 64 + (l & 15)) * 64 + (l >> 4) * 16;

    int nIter = chunk >> 5;

    // preload iter 0 into buf 0
    glds16(gA, &lds[0][0][w * 1024]);
    glds16(gA + rowJump, &lds[0][0][w * 1024 + 4096]);
    glds16(gB, &lds[0][1][w * 1024]);
    glds16(gB + rowJump, &lds[0][1][w * 1024 + 4096]);
    __syncthreads();

    for (int kb = 0; kb < nIter; ++kb) {
        int cur = kb & 1;
        if (kb + 1 < nIter) {
            const char* pa = gA + (size_t)(kb + 1) * 64;
            const char* pb = gB + (size_t)(kb + 1) * 64;
            char* la = &lds[cur ^ 1][0][w * 1024];
            char* lb = &lds[cur ^ 1][1][w * 1024];
            glds16(pa, la);
            glds16(pa + rowJump, la + 4096);
            glds16(pb, lb);
            glds16(pb + rowJump, lb + 4096);
        }
        const char* bufA = lds[cur][0];
        const char* bufB = lds[cur][1];
        bf16x8 af[4], bf[4];
#pragma unroll
        for (int mi = 0; mi < 4; ++mi) af[mi] = *(const bf16x8*)(bufA + aoff + mi * 1024);
#pragma unroll
        for (int ni = 0; ni < 4; ++ni) bf[ni] = *(const bf16x8*)(bufB + boff + ni * 1024);
#pragma unroll
        for (int mi = 0; mi < 4; ++mi)
#pragma unroll
            for (int ni = 0; ni < 4; ++ni)
                acc[mi][ni] = __builtin_amdgcn_mfma_f32_16x16x32_bf16(af[mi], bf[ni], acc[mi][ni], 0, 0, 0);
        __syncthreads();
    }

    // D layout: col = lane&15, row = (lane>>4)*4 + reg
    int q = l >> 4, c = l & 15;
    size_t base = (size_t)s << 20;  // s * 1024 * 1024
#pragma unroll
    for (int mi = 0; mi < 4; ++mi) {
        int rowG = tm * 128 + wm * 64 + mi * 16 + q * 4;
#pragma unroll
        for (int ni = 0; ni < 4; ++ni) {
            int colG = tn * 128 + wn * 64 + ni * 16 + c;
#pragma unroll
            for (int r = 0; r < 4; ++r)
                P[base + (size_t)(rowG + r) * 1024 + colG] = acc[mi][ni][r];
        }
    }
}

// ---------------- reduce partials + bias + optional ReLU -> bf16 ----------------
// P fp32 [S][1024][1024], out bf16 [1024][1024]
__global__ __launch_bounds__(256) void reduce_k(const float* __restrict__ P,
                                                const float* __restrict__ bias,
                                                BF16* __restrict__ out,
                                                int S, int relu) {
    int i = blockIdx.x * 256 + threadIdx.x;
    float a = bias[i & 1023];
    for (int s = 0; s < S; ++s) a += P[((size_t)s << 20) + i];
    if (relu) a = fmaxf(a, 0.0f);
    out[i] = __float2bfloat16(a);
}

// ---------------- cls/bbox heads + softmax + decode ----------------
__global__ __launch_bounds__(256) void head_k(const BF16* __restrict__ h2,
                                              const float* __restrict__ cls_w,
                                              const float* __restrict__ cls_b,
                                              const float* __restrict__ bbox_w,
                                              const float* __restrict__ bbox_b,
                                              const float* __restrict__ boxes,
                                              float* __restrict__ out) {
    int w = threadIdx.x >> 6, l = threadIdx.x & 63;
    int roi = blockIdx.x * 4 + w;
    if (roi >= 1000) return;
    float acc[10];
#pragma unroll
    for (int j = 0; j < 10; ++j) acc[j] = 0.0f;
    const BF16* hr = h2 + (size_t)roi * 1024;
    for (int k = l; k < 1024; k += 64) {
        float h = __bfloat162float(hr[k]);
        acc[0] += h * cls_w[k * 2 + 0];
        acc[1] += h * cls_w[k * 2 + 1];
#pragma unroll
        for (int j = 0; j < 8; ++j) acc[2 + j] += h * bbox_w[k * 8 + j];
    }
#pragma unroll
    for (int j = 0; j < 10; ++j) {
#pragma unroll
        for (int off = 32; off > 0; off >>= 1) acc[j] += __shfl_down(acc[j], off);
    }
    if (l == 0) {
        float s0 = acc[0] + cls_b[0], s1 = acc[1] + cls_b[1];
        float m = fmaxf(s0, s1);
        float e0 = expf(s0 - m), e1 = expf(s1 - m);
        float inv = 1.0f / (e0 + e1);

        float bx1 = boxes[roi * 4 + 0], by1 = boxes[roi * 4 + 1];
        float bx2 = boxes[roi * 4 + 2], by2 = boxes[roi * 4 + 3];
        float pw = bx2 - bx1, ph = by2 - by1;
        float cx = bx1 + 0.5f * pw, cy = by1 + 0.5f * ph;
        const float CLAMPV = 4.135166556742356f;  // log(1000/16)
        float* orow = out + roi * 10;
#pragma unroll
        for (int cl = 0; cl < 2; ++cl) {
            float dx = (acc[2 + cl * 4 + 0] + bbox_b[cl * 4 + 0]) * 0.1f;
            float dy = (acc[2 + cl * 4 + 1] + bbox_b[cl * 4 + 1]) * 0.1f;
            float dw = fminf((acc[2 + cl * 4 + 2] + bbox_b[cl * 4 + 2]) * 0.2f, CLAMPV);
            float dh = fminf((acc[2 + cl * 4 + 3] + bbox_b[cl * 4 + 3]) * 0.2f, CLAMPV);
            float pcx = dx * pw + cx, pcy = dy * ph + cy;
            float pww = expf(dw) * pw, phh = expf(dh) * ph;
            orow[cl * 4 + 0] = fminf(fmaxf(pcx - 0.5f * pww, 0.0f), 1088.0f);
            orow[cl * 4 + 1] = fminf(fmaxf(pcy - 0.5f * phh, 0.0f), 800.0f);
            orow[cl * 4 + 2] = fminf(fmaxf(pcx + 0.5f * pww, 0.0f), 1088.0f);
            orow[cl * 4 + 3] = fminf(fmaxf(pcy + 0.5f * phh, 0.0f), 800.0f);
        }
        orow[8] = e0 * inv;
        orow[9] = e1 * inv;
    }
}

extern "C" void kernel_launch(void* const* d_in, const int* in_sizes, int n_in,
                              void* d_out, int out_size, void* d_ws, size_t ws_size,
                              hipStream_t stream) {
    const float* features = (const float*)d_in[0];
    const float* boxes    = (const float*)d_in[1];
    const int*   roi_b    = (const int*)d_in[2];
    const float* fc1_w    = (const float*)d_in[3];
    const float* fc1_b    = (const float*)d_in[4];
    const float* fc2_w    = (const float*)d_in[5];
    const float* fc2_b    = (const float*)d_in[6];
    const float* cls_w    = (const float*)d_in[7];
    const float* cls_b    = (const float*)d_in[8];
    const float* bbox_w   = (const float*)d_in[9];
    const float* bbox_b   = (const float*)d_in[10];
    float* out = (float*)d_out;

    char* ws = (char*)d_ws;
    BF16* featT = (BF16*)(ws + 0);           // 2*100*136*256*2  = 13,926,400 B
    BF16* w1t   = (BF16*)(ws + 13926400);    // 1024*12544*2     = 25,690,112 B
    BF16* w2t   = (BF16*)(ws + 39616512);    // 1024*1024*2      =  2,097,152 B
    BF16* feats = (BF16*)(ws + 41713664);    // 1024*12544*2     = 25,690,112 B
    BF16* h1    = (BF16*)(ws + 67403776);    // 1024*1024*2      =  2,097,152 B
    BF16* h2    = (BF16*)(ws + 69500928);    // 1024*1024*2      =  2,097,152 B
    float* P    = (float*)(ws + 71598080);   // S*1024*1024*4

    // pick split factor to fit workspace (deterministic: ws_size fixed per run)
    size_t avail = (ws_size > 71598080) ? ws_size - 71598080 : 0;
    int S = 8;
    if (avail < (size_t)8 * 4194304) S = 4;
    if (avail < (size_t)4 * 4194304) S = 2;

    // features [2,256,13600] -> featT [2,13600,256] bf16
    transpose_cvt<<<dim3(425, 8, 2), 256, 0, stream>>>(features, featT, 256, 13600);
    // fc1_w [12544,1024] -> w1t [1024,12544] bf16
    transpose_cvt<<<dim3(32, 392, 1), 256, 0, stream>>>(fc1_w, w1t, 12544, 1024);
    // fc2_w [1024,1024] -> w2t [1024,1024] bf16
    transpose_cvt<<<dim3(32, 32, 1), 256, 0, stream>>>(fc2_w, w2t, 1024, 1024);

    roi_align_k<<<1024, 256, 0, stream>>>(featT, boxes, roi_b, feats);

    gemm_splitk<<<dim3(8, 8, S), 256, 0, stream>>>(feats, w1t, P, 12544, 12544 / S);
    reduce_k<<<4096, 256, 0, stream>>>(P, fc1_b, h1, S, 1);

    gemm_splitk<<<dim3(8, 8, S), 256, 0, stream>>>(h1, w2t, P, 1024, 1024 / S);
    reduce_k<<<4096, 256, 0, stream>>>(P, fc2_b, h2, S, 1);

    head_k<<<250, 256, 0, stream>>>(h2, cls_w, cls_b, bbox_w, bbox_b, boxes, out);
}

// Round 3
// 244.250 us; speedup vs baseline: 1.4775x; 1.1020x over previous
//
#include <hip/hip_runtime.h>
#include <hip/hip_bf16.h>

#define BF16 __hip_bfloat16

typedef __bf16 bf16x8 __attribute__((ext_vector_type(8)));
typedef float floatx4 __attribute__((ext_vector_type(4)));

struct __align__(8) bf4 { BF16 a, b, c, d; };

__device__ __forceinline__ void glds16(const void* g, void* l) {
    __builtin_amdgcn_global_load_lds(
        (const __attribute__((address_space(1))) void*)g,
        (__attribute__((address_space(3))) void*)l, 16, 0, 0);
}

// ---------------- transpose + fp32->bf16 convert ----------------
// in: fp32 [z][R][C], out: bf16 [z][C][R].  R,C multiples of 32.
__global__ __launch_bounds__(256) void transpose_cvt(const float* __restrict__ in,
                                                     BF16* __restrict__ out,
                                                     int R, int C) {
    __shared__ float tile[32][33];
    size_t boff = (size_t)blockIdx.z * R * C;
    const float* ip = in + boff;
    BF16* op = out + boff;
    int tx = threadIdx.x & 31, ty = threadIdx.x >> 5;
    int r0 = blockIdx.y << 5, c0 = blockIdx.x << 5;
#pragma unroll
    for (int i = 0; i < 4; ++i)
        tile[ty + i * 8][tx] = ip[(size_t)(r0 + ty + i * 8) * C + c0 + tx];
    __syncthreads();
#pragma unroll
    for (int i = 0; i < 4; ++i)
        op[(size_t)(c0 + ty + i * 8) * R + r0 + tx] = __float2bfloat16(tile[tx][ty + i * 8]);
}

// ---------------- ROI align (phase-split, vectorized) ----------------
// featT bf16 [B][100][136][256]; feats bf16 [1024][12544] (rows >=1000 zeroed)
// Phase 1: 196 threads precompute tap offsets/weights into LDS.
// Phase 2: thread = (cell-group t>>6, channel-quad t&63); bf16x4 tap loads.
__global__ __launch_bounds__(256) void roi_align_k(const BF16* __restrict__ featT,
                                                   const float* __restrict__ boxes,
                                                   const int* __restrict__ roi_batch,
                                                   BF16* __restrict__ feats) {
    __shared__ __align__(16) int   s_off[196][4];
    __shared__ __align__(16) float s_w[196][4];
    __shared__ BF16 lbuf[12544];  // bf16 staging, 25 KB
    int roi = blockIdx.x;
    int t = threadIdx.x;
    BF16* orow = feats + (size_t)roi * 12544;
    if (roi >= 1000) {
        uint* o4 = (uint*)orow;
        for (int i = t; i < 6272; i += 256) o4[i] = 0u;
        return;
    }
    int b = roi_batch[roi];

    if (t < 196) {
        float x1 = boxes[roi * 4 + 0] * 0.125f;
        float y1 = boxes[roi * 4 + 1] * 0.125f;
        float x2 = boxes[roi * 4 + 2] * 0.125f;
        float y2 = boxes[roi * 4 + 3] * 0.125f;
        float bw = fmaxf(x2 - x1, 1.0f) * (1.0f / 7.0f);
        float bh = fmaxf(y2 - y1, 1.0f) * (1.0f / 7.0f);
        int cell = t >> 2, s = t & 3;
        int oy = cell / 7, ox = cell - oy * 7;
        int sy = s >> 1, sx = s & 1;
        float yc = y1 + ((float)oy + ((float)sy + 0.5f) * 0.5f) * bh;
        float xc = x1 + ((float)ox + ((float)sx + 0.5f) * 0.5f) * bw;
        yc = fminf(fmaxf(yc, 0.0f), 99.0f);
        xc = fminf(fmaxf(xc, 0.0f), 135.0f);
        float y0f = floorf(yc), x0f = floorf(xc);
        int y0 = (int)y0f, x0 = (int)x0f;
        int y1i = min(y0 + 1, 99), x1i = min(x0 + 1, 135);
        float ly = yc - y0f, lx = xc - x0f;
        s_w[t][0] = (1.0f - ly) * (1.0f - lx) * 0.25f;
        s_w[t][1] = (1.0f - ly) * lx * 0.25f;
        s_w[t][2] = ly * (1.0f - lx) * 0.25f;
        s_w[t][3] = ly * lx * 0.25f;
        s_off[t][0] = (y0 * 136 + x0) * 256;
        s_off[t][1] = (y0 * 136 + x1i) * 256;
        s_off[t][2] = (y1i * 136 + x0) * 256;
        s_off[t][3] = (y1i * 136 + x1i) * 256;
    }
    __syncthreads();

    int lane = t & 63, cg = t >> 6;   // cg is wave-uniform -> LDS broadcasts
    const BF16* fb = featT + (size_t)b * (100 * 136 * 256) + lane * 4;
    int cbase = lane * 4;
    for (int cell = cg; cell < 49; cell += 4) {
        float a0 = 0.f, a1 = 0.f, a2 = 0.f, a3 = 0.f;
#pragma unroll
        for (int s = 0; s < 4; ++s) {
            int p = cell * 4 + s;
#pragma unroll
            for (int tap = 0; tap < 4; ++tap) {
                float w = s_w[p][tap];
                bf4 v = *(const bf4*)(fb + s_off[p][tap]);
                a0 += w * __bfloat162float(v.a);
                a1 += w * __bfloat162float(v.b);
                a2 += w * __bfloat162float(v.c);
                a3 += w * __bfloat162float(v.d);
            }
        }
        lbuf[(cbase + 0) * 49 + cell] = __float2bfloat16(a0);
        lbuf[(cbase + 1) * 49 + cell] = __float2bfloat16(a1);
        lbuf[(cbase + 2) * 49 + cell] = __float2bfloat16(a2);
        lbuf[(cbase + 3) * 49 + cell] = __float2bfloat16(a3);
    }
    __syncthreads();
    uint* o4 = (uint*)orow;
    const uint* l4 = (const uint*)lbuf;
    for (int i = t; i < 6272; i += 256) o4[i] = l4[i];
}

// ---------------- split-K bf16 MFMA GEMM, 128x128 tile, double-buffered ----------------
// A bf16 [1024][K], Bt bf16 [1024][K] (N=1024), P fp32 [S][1024][1024] partials.
// grid (8, 8, S); chunk = K/S, chunk % 32 == 0. 256 threads = 4 waves in 2x2.
__global__ __launch_bounds__(256) void gemm_splitk(const BF16* __restrict__ A,
                                                   const BF16* __restrict__ Bt,
                                                   float* __restrict__ P,
                                                   int K, int chunk) {
    __shared__ char lds[2][2][8192];  // [buf][A=0/B=1][128 rows x 64 B]
    int w = threadIdx.x >> 6, l = threadIdx.x & 63;
    int wm = w & 1, wn = w >> 1;
    int tm = blockIdx.y, tn = blockIdx.x, s = blockIdx.z;
    int k0 = s * chunk;

    floatx4 acc[4][4];
#pragma unroll
    for (int i = 0; i < 4; ++i)
#pragma unroll
        for (int j = 0; j < 4; ++j) acc[i][j] = (floatx4){0.f, 0.f, 0.f, 0.f};

    const size_t strideA = (size_t)K * 2;  // bytes per row
    const char* gA = (const char*)A + (size_t)(tm * 128 + w * 16 + (l >> 2)) * strideA
                     + (size_t)k0 * 2 + (size_t)(l & 3) * 16;
    const char* gB = (const char*)Bt + (size_t)(tn * 128 + w * 16 + (l >> 2)) * strideA
                     + (size_t)k0 * 2 + (size_t)(l & 3) * 16;
    size_t rowJump = 64 * strideA;  // +64 rows for second staging issue

    int aoff = (wm * 64 + (l & 15)) * 64 + (l >> 4) * 16;
    int boff = (wn * 64 + (l & 15)) * 64 + (l >> 4) * 16;

    int nIter = chunk >> 5;

    // preload iter 0 into buf 0
    glds16(gA, &lds[0][0][w * 1024]);
    glds16(gA + rowJump, &lds[0][0][w * 1024 + 4096]);
    glds16(gB, &lds[0][1][w * 1024]);
    glds16(gB + rowJump, &lds[0][1][w * 1024 + 4096]);
    __syncthreads();

    for (int kb = 0; kb < nIter; ++kb) {
        int cur = kb & 1;
        if (kb + 1 < nIter) {
            const char* pa = gA + (size_t)(kb + 1) * 64;
            const char* pb = gB + (size_t)(kb + 1) * 64;
            char* la = &lds[cur ^ 1][0][w * 1024];
            char* lb = &lds[cur ^ 1][1][w * 1024];
            glds16(pa, la);
            glds16(pa + rowJump, la + 4096);
            glds16(pb, lb);
            glds16(pb + rowJump, lb + 4096);
        }
        const char* bufA = lds[cur][0];
        const char* bufB = lds[cur][1];
        bf16x8 af[4], bf[4];
#pragma unroll
        for (int mi = 0; mi < 4; ++mi) af[mi] = *(const bf16x8*)(bufA + aoff + mi * 1024);
#pragma unroll
        for (int ni = 0; ni < 4; ++ni) bf[ni] = *(const bf16x8*)(bufB + boff + ni * 1024);
#pragma unroll
        for (int mi = 0; mi < 4; ++mi)
#pragma unroll
            for (int ni = 0; ni < 4; ++ni)
                acc[mi][ni] = __builtin_amdgcn_mfma_f32_16x16x32_bf16(af[mi], bf[ni], acc[mi][ni], 0, 0, 0);
        __syncthreads();
    }

    // D layout: col = lane&15, row = (lane>>4)*4 + reg
    int q = l >> 4, c = l & 15;
    size_t base = (size_t)s << 20;  // s * 1024 * 1024
#pragma unroll
    for (int mi = 0; mi < 4; ++mi) {
        int rowG = tm * 128 + wm * 64 + mi * 16 + q * 4;
#pragma unroll
        for (int ni = 0; ni < 4; ++ni) {
            int colG = tn * 128 + wn * 64 + ni * 16 + c;
#pragma unroll
            for (int r = 0; r < 4; ++r)
                P[base + (size_t)(rowG + r) * 1024 + colG] = acc[mi][ni][r];
        }
    }
}

// ---------------- reduce partials + bias + optional ReLU -> bf16 ----------------
// P fp32 [S][1024][1024], out bf16 [1024][1024]
__global__ __launch_bounds__(256) void reduce_k(const float* __restrict__ P,
                                                const float* __restrict__ bias,
                                                BF16* __restrict__ out,
                                                int S, int relu) {
    int i = blockIdx.x * 256 + threadIdx.x;
    float a = bias[i & 1023];
    for (int s = 0; s < S; ++s) a += P[((size_t)s << 20) + i];
    if (relu) a = fmaxf(a, 0.0f);
    out[i] = __float2bfloat16(a);
}

// ---------------- cls/bbox heads + softmax + decode ----------------
__global__ __launch_bounds__(256) void head_k(const BF16* __restrict__ h2,
                                              const float* __restrict__ cls_w,
                                              const float* __restrict__ cls_b,
                                              const float* __restrict__ bbox_w,
                                              const float* __restrict__ bbox_b,
                                              const float* __restrict__ boxes,
                                              float* __restrict__ out) {
    int w = threadIdx.x >> 6, l = threadIdx.x & 63;
    int roi = blockIdx.x * 4 + w;
    if (roi >= 1000) return;
    float acc[10];
#pragma unroll
    for (int j = 0; j < 10; ++j) acc[j] = 0.0f;
    const BF16* hr = h2 + (size_t)roi * 1024;
    for (int k = l; k < 1024; k += 64) {
        float h = __bfloat162float(hr[k]);
        acc[0] += h * cls_w[k * 2 + 0];
        acc[1] += h * cls_w[k * 2 + 1];
#pragma unroll
        for (int j = 0; j < 8; ++j) acc[2 + j] += h * bbox_w[k * 8 + j];
    }
#pragma unroll
    for (int j = 0; j < 10; ++j) {
#pragma unroll
        for (int off = 32; off > 0; off >>= 1) acc[j] += __shfl_down(acc[j], off);
    }
    if (l == 0) {
        float s0 = acc[0] + cls_b[0], s1 = acc[1] + cls_b[1];
        float m = fmaxf(s0, s1);
        float e0 = expf(s0 - m), e1 = expf(s1 - m);
        float inv = 1.0f / (e0 + e1);

        float bx1 = boxes[roi * 4 + 0], by1 = boxes[roi * 4 + 1];
        float bx2 = boxes[roi * 4 + 2], by2 = boxes[roi * 4 + 3];
        float pw = bx2 - bx1, ph = by2 - by1;
        float cx = bx1 + 0.5f * pw, cy = by1 + 0.5f * ph;
        const float CLAMPV = 4.135166556742356f;  // log(1000/16)
        float* orow = out + roi * 10;
#pragma unroll
        for (int cl = 0; cl < 2; ++cl) {
            float dx = (acc[2 + cl * 4 + 0] + bbox_b[cl * 4 + 0]) * 0.1f;
            float dy = (acc[2 + cl * 4 + 1] + bbox_b[cl * 4 + 1]) * 0.1f;
            float dw = fminf((acc[2 + cl * 4 + 2] + bbox_b[cl * 4 + 2]) * 0.2f, CLAMPV);
            float dh = fminf((acc[2 + cl * 4 + 3] + bbox_b[cl * 4 + 3]) * 0.2f, CLAMPV);
            float pcx = dx * pw + cx, pcy = dy * ph + cy;
            float pww = expf(dw) * pw, phh = expf(dh) * ph;
            orow[cl * 4 + 0] = fminf(fmaxf(pcx - 0.5f * pww, 0.0f), 1088.0f);
            orow[cl * 4 + 1] = fminf(fmaxf(pcy - 0.5f * phh, 0.0f), 800.0f);
            orow[cl * 4 + 2] = fminf(fmaxf(pcx + 0.5f * pww, 0.0f), 1088.0f);
            orow[cl * 4 + 3] = fminf(fmaxf(pcy + 0.5f * phh, 0.0f), 800.0f);
        }
        orow[8] = e0 * inv;
        orow[9] = e1 * inv;
    }
}

extern "C" void kernel_launch(void* const* d_in, const int* in_sizes, int n_in,
                              void* d_out, int out_size, void* d_ws, size_t ws_size,
                              hipStream_t stream) {
    const float* features = (const float*)d_in[0];
    const float* boxes    = (const float*)d_in[1];
    const int*   roi_b    = (const int*)d_in[2];
    const float* fc1_w    = (const float*)d_in[3];
    const float* fc1_b    = (const float*)d_in[4];
    const float* fc2_w    = (const float*)d_in[5];
    const float* fc2_b    = (const float*)d_in[6];
    const float* cls_w    = (const float*)d_in[7];
    const float* cls_b    = (const float*)d_in[8];
    const float* bbox_w   = (const float*)d_in[9];
    const float* bbox_b   = (const float*)d_in[10];
    float* out = (float*)d_out;

    char* ws = (char*)d_ws;
    BF16* featT = (BF16*)(ws + 0);           // 2*100*136*256*2  = 13,926,400 B
    BF16* w1t   = (BF16*)(ws + 13926400);    // 1024*12544*2     = 25,690,112 B
    BF16* w2t   = (BF16*)(ws + 39616512);    // 1024*1024*2      =  2,097,152 B
    BF16* feats = (BF16*)(ws + 41713664);    // 1024*12544*2     = 25,690,112 B
    BF16* h1    = (BF16*)(ws + 67403776);    // 1024*1024*2      =  2,097,152 B
    BF16* h2    = (BF16*)(ws + 69500928);    // 1024*1024*2      =  2,097,152 B
    float* P    = (float*)(ws + 71598080);   // S*1024*1024*4

    // pick split factor to fit workspace (deterministic: ws_size fixed per run)
    size_t avail = (ws_size > 71598080) ? ws_size - 71598080 : 0;
    int S = 8;
    if (avail < (size_t)8 * 4194304) S = 4;
    if (avail < (size_t)4 * 4194304) S = 2;

    // features [2,256,13600] -> featT [2,13600,256] bf16
    transpose_cvt<<<dim3(425, 8, 2), 256, 0, stream>>>(features, featT, 256, 13600);
    // fc1_w [12544,1024] -> w1t [1024,12544] bf16
    transpose_cvt<<<dim3(32, 392, 1), 256, 0, stream>>>(fc1_w, w1t, 12544, 1024);
    // fc2_w [1024,1024] -> w2t [1024,1024] bf16
    transpose_cvt<<<dim3(32, 32, 1), 256, 0, stream>>>(fc2_w, w2t, 1024, 1024);

    roi_align_k<<<1024, 256, 0, stream>>>(featT, boxes, roi_b, feats);

    gemm_splitk<<<dim3(8, 8, S), 256, 0, stream>>>(feats, w1t, P, 12544, 12544 / S);
    reduce_k<<<4096, 256, 0, stream>>>(P, fc1_b, h1, S, 1);

    gemm_splitk<<<dim3(8, 8, S), 256, 0, stream>>>(h1, w2t, P, 1024, 1024 / S);
    reduce_k<<<4096, 256, 0, stream>>>(P, fc2_b, h2, S, 1);

    head_k<<<250, 256, 0, stream>>>(h2, cls_w, cls_b, bbox_w, bbox_b, boxes, out);
}